// Round 5
// baseline (279.096 us; speedup 1.0000x reference)
//
#include <hip/hip_runtime.h>
#include <hip/hip_bf16.h>

// Inputs (f32): fm [64][768][676], att_w [192][768], att_b [192],
//               fc_w [200][24576], fc_b [200]
// d_out (f32): p [64*200] | fm_n [64*32*768] | att_m [64*32*676]
// ws: fmb16 bf16 [64][768][704] (64B-aligned rows, zero pad) |
//     {att_pad bf16 [64][32][704] UNION p_part f32 [48][64][208]} |
//     pooled f32 [64][32][768] | fmn16 bf16 [64*24576] | p_sums f32 [64]
// Strategy: one streaming f32->bf16 pass makes both big GEMM passes read
// aligned bf16 (half traffic, no converts, no line-straddle overfetch).

typedef unsigned short u16;
typedef __bf16 bf16x8_t __attribute__((ext_vector_type(8)));
typedef float f32x4_t __attribute__((ext_vector_type(4)));
typedef unsigned int uint32x4 __attribute__((ext_vector_type(4)));
typedef unsigned int uint32x2 __attribute__((ext_vector_type(2)));

union Frag { uint32x4 u4; unsigned u[4]; u16 s[8]; bf16x8_t v; };
union BFU { __hip_bfloat16 h; u16 u; };

__device__ inline u16 f2b(float x) { BFU t; t.h = __float2bfloat16(x); return t.u; }

__device__ inline void load8_cvt(const float* p, Frag& f) {
    f32x4_t x0 = *(const f32x4_t*)(p);
    f32x4_t x1 = *(const f32x4_t*)(p + 4);
#pragma unroll
    for (int j = 0; j < 4; ++j) { f.s[j] = f2b(x0[j]); f.s[4 + j] = f2b(x1[j]); }
}

#define MFMA(a, b, c) __builtin_amdgcn_mfma_f32_16x16x32_bf16((a), (b), (c), 0, 0, 0)

// ---------------- Pass 0: fm f32 -> fmb16 bf16, rows padded 676->704 ----------------
// One float4 slot per thread; 176 slots/row (169 data + 7 zero-pad).
__global__ __launch_bounds__(256) void k_cvt(
    const float* __restrict__ fm, u16* __restrict__ fmb16,
    float* __restrict__ p_sums)
{
    const int tid = blockIdx.x * 256 + threadIdx.x;   // 33792*256 = 64*768*176
    if (blockIdx.x == 0 && threadIdx.x < 64) p_sums[threadIdx.x] = 0.f;
    const int cp  = tid % 176;
    const int row = tid / 176;                         // 0..49151 = b*768+c
    u16* dst = fmb16 + (size_t)row * 704 + cp * 4;
    uint32x2 w;
    if (cp < 169) {
        f32x4_t x = *(const f32x4_t*)(fm + (size_t)row * 676 + cp * 4);
        w[0] = (unsigned)f2b(x[0]) | ((unsigned)f2b(x[1]) << 16);
        w[1] = (unsigned)f2b(x[2]) | ((unsigned)f2b(x[3]) << 16);
    } else {
        w[0] = 0u; w[1] = 0u;
    }
    *(uint32x2*)dst = w;
}

// ---------------- Pass 1: att = relu(att_w[:32] @ fm[b] + att_b) ----------------
// grid (11, 64). Tile 32m x 64p. Wave wv owns K-chunk [wv*192, +192); no barriers
// in K-loop. B-frags: aligned bf16 scalar loads (rows 1408B = 64B-aligned; pad
// cols are zero so no edge cases). A = att_w f32 + inline cvt (L2-hot).
__global__ __launch_bounds__(256) void k_att(
    const u16* __restrict__ fmb16, const float* __restrict__ att_w,
    const float* __restrict__ att_b, float* __restrict__ att_out,
    __hip_bfloat16* __restrict__ att_pad)
{
    const int b  = blockIdx.y;
    const int p0 = blockIdx.x << 6;          // 11 tiles of 64 -> 0..640 (704 padded)
    const int t  = threadIdx.x;
    const int wv = t >> 6, l = t & 63, q = l >> 4, ln = l & 15;

    __shared__ float red[32][64][4];         // [m][p_local][wave], 32 KB

    f32x4_t acc[2][4];
#pragma unroll
    for (int i = 0; i < 2; ++i)
#pragma unroll
        for (int j = 0; j < 4; ++j) acc[i][j] = f32x4_t{0.f, 0.f, 0.f, 0.f};

    const int kb = wv * 192;
    const u16* Bbase = fmb16 + (size_t)b * 768 * 704 + p0;

#pragma unroll
    for (int it = 0; it < 6; ++it) {
        const int k0 = kb + it * 32;
        Frag a0, a1, bf[4];
        load8_cvt(att_w + (size_t)ln * 768 + k0 + q * 8, a0);          // m 0..15
        load8_cvt(att_w + (size_t)(16 + ln) * 768 + k0 + q * 8, a1);   // m 16..31
        const u16* bp = Bbase + (size_t)(k0 + q * 8) * 704 + ln;
#pragma unroll
        for (int pc = 0; pc < 4; ++pc)
#pragma unroll
            for (int j = 0; j < 8; ++j)
                bf[pc].s[j] = bp[(size_t)j * 704 + pc * 16];
#pragma unroll
        for (int pc = 0; pc < 4; ++pc) {
            acc[0][pc] = MFMA(a0.v, bf[pc].v, acc[0][pc]);
            acc[1][pc] = MFMA(a1.v, bf[pc].v, acc[1][pc]);
        }
    }

#pragma unroll
    for (int mh = 0; mh < 2; ++mh)
#pragma unroll
        for (int pc = 0; pc < 4; ++pc)
#pragma unroll
            for (int r = 0; r < 4; ++r)
                red[mh * 16 + q * 4 + r][pc * 16 + ln][wv] = acc[mh][pc][r];
    __syncthreads();

    // epilogue: thread t -> m = t>>3, 8 consecutive p starting at (t&7)*8
    const int m  = t >> 3;
    const int pg = (t & 7) << 3;
    const float bias = att_b[m];
#pragma unroll
    for (int g = 0; g < 2; ++g) {
        const int pl = pg + g * 4;
        const int p  = p0 + pl;
        f32x4_t v;
        u16 h[4];
#pragma unroll
        for (int j = 0; j < 4; ++j) {
            f32x4_t r4 = *(const f32x4_t*)&red[m][pl + j][0];
            float x = r4[0] + r4[1] + r4[2] + r4[3] + bias;
            x = x > 0.f ? x : 0.f;
            v[j] = x;
            h[j] = (p + j < 676) ? f2b(x) : (u16)0;
        }
        if (p <= 672)   // p..p+3 all < 676
            *(f32x4_t*)(att_out + (size_t)(b * 32 + m) * 676 + p) = v;
        uint32x2 w;
        w[0] = (unsigned)h[0] | ((unsigned)h[1] << 16);
        w[1] = (unsigned)h[2] | ((unsigned)h[3] << 16);
        *(uint32x2*)((u16*)att_pad + (size_t)(b * 32 + m) * 704 + p) = w;
    }
}

// ---------------- Pass 2: pooled[b] = att[b](32x704) @ fm[b]^T / 676 ----------------
// grid (24, 64). Tile 32m x 32c. 22 k-steps striped across 4 waves; no barriers
// in loop. All-bf16 direct dwordx4 loads; pad cols zero on BOTH operands.
// Fuses Sum|pooled| into p_sums[b] (one atomicAdd per block).
__global__ __launch_bounds__(256) void k_pool(
    const u16* __restrict__ fmb16, const u16* __restrict__ att_pad,
    float* __restrict__ pooled, float* __restrict__ p_sums)
{
    const int b  = blockIdx.y;
    const int n0 = blockIdx.x << 5;          // 24 tiles of 32
    const int t  = threadIdx.x;
    const int wv = t >> 6, l = t & 63, q = l >> 4, ln = l & 15;

    __shared__ float red[32][32][4];
    __shared__ float rs[4];

    const u16* Ab = att_pad + (size_t)b * 32 * 704;
    const u16* B0 = fmb16 + (size_t)(b * 768 + n0 + ln) * 704;
    const u16* B1 = fmb16 + (size_t)(b * 768 + n0 + 16 + ln) * 704;

    f32x4_t acc[2][2] = {{{0.f,0.f,0.f,0.f},{0.f,0.f,0.f,0.f}},
                         {{0.f,0.f,0.f,0.f},{0.f,0.f,0.f,0.f}}};

    for (int it = wv; it < 22; it += 4) {
        const int k = it * 32 + q * 8;
        Frag a0, a1, b0, b1;
        a0.u4 = *(const uint32x4*)(Ab + (size_t)ln * 704 + k);
        a1.u4 = *(const uint32x4*)(Ab + (size_t)(16 + ln) * 704 + k);
        b0.u4 = *(const uint32x4*)(B0 + k);
        b1.u4 = *(const uint32x4*)(B1 + k);
        acc[0][0] = MFMA(a0.v, b0.v, acc[0][0]);
        acc[0][1] = MFMA(a0.v, b1.v, acc[0][1]);
        acc[1][0] = MFMA(a1.v, b0.v, acc[1][0]);
        acc[1][1] = MFMA(a1.v, b1.v, acc[1][1]);
    }

#pragma unroll
    for (int mh = 0; mh < 2; ++mh)
#pragma unroll
        for (int ch = 0; ch < 2; ++ch)
#pragma unroll
            for (int r = 0; r < 4; ++r)
                red[mh * 16 + q * 4 + r][ch * 16 + ln][wv] = acc[mh][ch][r];
    __syncthreads();

    const float sc = 1.0f / 676.0f;
    const int m = t >> 3, c0 = (t & 7) << 2;
    float ls = 0.f;
#pragma unroll
    for (int j = 0; j < 4; ++j) {
        const int cl = c0 + j;
        f32x4_t v4 = *(const f32x4_t*)&red[m][cl][0];
        float v = (v4[0] + v4[1] + v4[2] + v4[3]) * sc;
        pooled[(size_t)(b * 32 + m) * 768 + n0 + cl] = v;
        ls += fabsf(v);
    }
    for (int off = 32; off > 0; off >>= 1) ls += __shfl_down(ls, off);
    if (l == 0) rs[wv] = ls;
    __syncthreads();
    if (t == 0) atomicAdd(p_sums + b, rs[0] + rs[1] + rs[2] + rs[3]);
}

// ---------------- Pass 3 (apply only): signed sqrt + L2 normalize ----------------
__global__ __launch_bounds__(256) void k_norm(
    const float* __restrict__ pooled, const float* __restrict__ p_sums,
    float* __restrict__ fm_out, u16* __restrict__ fmn16)
{
    const int b = blockIdx.x;
    const size_t base = (size_t)b * 24576 + (size_t)blockIdx.y * 2048;
    const float tot = p_sums[b] + 24576.f * 1e-12f;
    const float inv = 1.f / fmaxf(sqrtf(tot), 1e-12f);
    const int t = threadIdx.x;
#pragma unroll
    for (int i = 0; i < 8; ++i) {
        const size_t idx = base + i * 256 + t;
        float x = pooled[idx];
        float v = (x == 0.f) ? 0.f : copysignf(sqrtf(fabsf(x) + 1e-12f), x);
        float o = v * inv;
        fm_out[idx] = o;
        fmn16[idx]  = f2b(o);
    }
}

// ---------------- Pass 4: p partials, K=24576 split into 48 slabs of 512 ----------------
__global__ __launch_bounds__(256) void k_fc(
    const u16* __restrict__ fmn16, const float* __restrict__ fc_w,
    float* __restrict__ p_part)
{
    const int ntile = blockIdx.x;          // 0..12
    const int slab  = blockIdx.y;          // 0..47
    const int t = threadIdx.x;
    const int wv = t >> 6, l = t & 63, q = l >> 4, ln = l & 15;
    const int n = ntile * 16 + ln;
    const int kbase = slab * 512;

    const u16*   Ab = fmn16 + (size_t)(wv * 16 + ln) * 24576 + kbase + q * 8;
    const float* Bb = fc_w + (size_t)n * 24576 + kbase + q * 8;
    const bool nok = n < 200;

    f32x4_t acc = {0.f, 0.f, 0.f, 0.f};
#pragma unroll
    for (int kk = 0; kk < 512; kk += 32) {
        Frag af, bf2;
        af.u4 = *(const uint32x4*)(Ab + kk);
        if (nok) load8_cvt(Bb + kk, bf2);
        else { bf2.u[0] = 0u; bf2.u[1] = 0u; bf2.u[2] = 0u; bf2.u[3] = 0u; }
        acc = MFMA(af.v, bf2.v, acc);
    }
#pragma unroll
    for (int r = 0; r < 4; ++r) {
        const int bb = wv * 16 + q * 4 + r;
        p_part[(size_t)(slab * 64 + bb) * 208 + ntile * 16 + ln] = acc[r];
    }
}

// ---------------- Pass 5: reduce 48 slabs, scale 100, + bias ----------------
__global__ __launch_bounds__(256) void k_fin(
    const float* __restrict__ p_part, const float* __restrict__ fc_b,
    float* __restrict__ p_out)
{
    const int tid = blockIdx.x * 256 + threadIdx.x;   // 50*256 == 12800
    const int b = tid / 200, n = tid - b * 200;
    float s = 0.f;
#pragma unroll
    for (int sl = 0; sl < 48; ++sl) s += p_part[(size_t)(sl * 64 + b) * 208 + n];
    p_out[tid] = s * 100.f + fc_b[n];
}

extern "C" void kernel_launch(void* const* d_in, const int* in_sizes, int n_in,
                              void* d_out, int out_size, void* d_ws, size_t ws_size,
                              hipStream_t stream)
{
    const float* fm    = (const float*)d_in[0];
    const float* att_w = (const float*)d_in[1];
    const float* att_b = (const float*)d_in[2];
    const float* fc_w  = (const float*)d_in[3];
    const float* fc_b  = (const float*)d_in[4];

    float* out     = (float*)d_out;
    float* p_out   = out;                         // [64][200]
    float* fm_out  = out + 12800;                 // [64][32][768]
    float* att_out = out + 12800 + 64 * 32 * 768; // [64][32][676]

    char* ws = (char*)d_ws;
    u16* fmb16 = (u16*)ws;                                   // 64*768*704*2 = 69,206,016 B
    // att_pad (2,883,584 B) and p_part (2,555,904 B): disjoint lifetimes -> overlay.
    __hip_bfloat16* att_pad = (__hip_bfloat16*)(ws + 69206016);
    float* p_part = (float*)(ws + 69206016);
    float* pooled = (float*)(ws + 69206016 + 2883584);       // 6,291,456 B
    u16*   fmn16  = (u16*)(ws + 69206016 + 2883584 + 6291456); // 3,145,728 B
    float* p_sums = (float*)(ws + 69206016 + 2883584 + 6291456 + 3145728); // 256 B

    k_cvt <<<dim3(33792), 256, 0, stream>>>(fm, fmb16, p_sums);
    k_att <<<dim3(11, 64), 256, 0, stream>>>(fmb16, att_w, att_b, att_out, att_pad);
    k_pool<<<dim3(24, 64), 256, 0, stream>>>(fmb16, (const u16*)att_pad, pooled, p_sums);
    k_norm<<<dim3(64, 12), 256, 0, stream>>>(pooled, p_sums, fm_out, fmn16);
    k_fc  <<<dim3(13, 48), 256, 0, stream>>>(fmn16, fc_w, p_part);
    k_fin <<<dim3(50),     256, 0, stream>>>(p_part, fc_b, p_out);
}